// Round 3
// baseline (373.945 us; speedup 1.0000x reference)
//
#include <hip/hip_runtime.h>
#include <math.h>

#define N_NODES 50000
#define N_EDGES 800000
#define IN_DIM  512
#define HID     128
#define OUT_DIM 64
#define EPS     0.3f

#define SCAN_BLOCKS 49   // ceil(50000 / 1024)
#define LDS_ROW 516      // 512 + 4 dword pad -> 2-way bank aliasing (free, m136)

typedef __attribute__((ext_vector_type(8))) short bf16x8;
typedef __attribute__((ext_vector_type(8))) __bf16 bf16v8;
typedef __attribute__((ext_vector_type(4))) float f32x4;

__device__ __forceinline__ float fast_tanh(float x) {
    // tanh(x) = 1 - 2/(exp(2x)+1); saturates correctly at +/-inf
    return 1.0f - 2.0f / (__expf(2.0f * x) + 1.0f);
}

// f32 -> bf16 via native cast: compiler emits v_cvt_pk_bf16_f32 (RNE).
__device__ __forceinline__ unsigned short f2bfu(float f) {
    return __builtin_bit_cast(unsigned short, (__bf16)f);
}
__device__ __forceinline__ unsigned pk2(float lo, float hi) {
    return (unsigned)f2bfu(lo) | ((unsigned)f2bfu(hi) << 16);
}
__device__ __forceinline__ float bf_lo(unsigned u) { return __uint_as_float(u << 16); }
__device__ __forceinline__ float bf_hi(unsigned u) { return __uint_as_float(u & 0xffff0000u); }

// degree recovered from input d = rsqrt(deg+1): deg = round(1/d^2) - 1.
__device__ __forceinline__ int deg_of(float dv) {
    return (int)(1.0f / (dv * dv) + 0.5f) - 1;
}

// ---------------- CSR build (no histogram: deg derived from d) ----------------

__global__ void partial_k(const float* __restrict__ d, int* __restrict__ partials) {
    int base = blockIdx.x * 1024 + threadIdx.x * 4;
    int s = 0;
#pragma unroll
    for (int j = 0; j < 4; j++) if (base + j < N_NODES) s += deg_of(d[base + j]);
#pragma unroll
    for (int off = 32; off; off >>= 1) s += __shfl_down(s, off);
    __shared__ int ws[4];
    int lane = threadIdx.x & 63, wv = threadIdx.x >> 6;
    if (lane == 0) ws[wv] = s;
    __syncthreads();
    if (threadIdx.x == 0) partials[blockIdx.x] = ws[0] + ws[1] + ws[2] + ws[3];
}

__global__ void scanp_k(const int* __restrict__ partials, int* __restrict__ bofs,
                        int* __restrict__ rowptr) {
    if (threadIdx.x == 0) {
        int a = 0;
        for (int i = 0; i < SCAN_BLOCKS; i++) { bofs[i] = a; a += partials[i]; }
        rowptr[N_NODES] = a;
    }
}

__global__ void scanw_k(const float* __restrict__ d, const int* __restrict__ bofs,
                        int* __restrict__ rowptr, int* __restrict__ cursor) {
    int base = blockIdx.x * 1024 + threadIdx.x * 4;
    int v[4]; int s = 0;
#pragma unroll
    for (int j = 0; j < 4; j++) {
        v[j] = (base + j < N_NODES) ? deg_of(d[base + j]) : 0;
        s += v[j];
    }
    int lane = threadIdx.x & 63, wv = threadIdx.x >> 6;
    int sc = s;
#pragma unroll
    for (int off = 1; off < 64; off <<= 1) {
        int t = __shfl_up(sc, off);
        if (lane >= off) sc += t;
    }
    __shared__ int wtot[4];
    if (lane == 63) wtot[wv] = sc;
    __syncthreads();
    int wof = 0;
    for (int w = 0; w < wv; w++) wof += wtot[w];
    int excl = bofs[blockIdx.x] + wof + (sc - s);
#pragma unroll
    for (int j = 0; j < 4; j++) {
        if (base + j < N_NODES) { rowptr[base + j] = excl; cursor[base + j] = excl; }
        excl += v[j];
    }
}

// CSR fill: ONE 8B scatter per edge -> {src|yn<<31, dst}. Same random-line count
// as a 4B store (R2 post-mortem: a second 4B array = +35us of partial-line HBM
// writes; packing dst into the same int2 is free).
__global__ void fill_k(const int* __restrict__ src, const int* __restrict__ dst,
                       const int* __restrict__ yn, int* __restrict__ cursor,
                       int2* __restrict__ csr2) {
    int e = blockIdx.x * blockDim.x + threadIdx.x;
    if (e >= N_EDGES) return;
    int dv = dst[e];
    int pos = atomicAdd(&cursor[dv], 1);
    csr2[pos] = make_int2(src[e] | (yn[e] << 31), dv);
}

// ---------------- per-layer edge coefficients (CSR order, edge-parallel) --------
// Hoists the tanh + gs/d gathers OUT of agg_k's latency-critical per-node loop.
// csr2 read is fully coalesced (8B/edge); gd/gs/d gathers hit 200KB L2-resident.
__global__ void coef_k(const int2* __restrict__ csr2,
                       const float* __restrict__ d,
                       const float* __restrict__ gd, const float* __restrict__ gs,
                       const float* __restrict__ gb, int layer,
                       const float* __restrict__ yw, const float* __restrict__ nw,
                       float* __restrict__ coef) {
    int e = blockIdx.x * blockDim.x + threadIdx.x;
    if (e >= N_EDGES) return;
    int2 pr = csr2[e];
    int s  = pr.x & 0xffff;          // src < 50000 < 2^16
    int dn = pr.y;
    float ty  = fast_tanh(yw[0]);
    float tno = fast_tanh(nw[0]);
    float ynt = (pr.x < 0) ? ty : tno;
    coef[e] = (fast_tanh(gd[dn] + gs[s] + gb[layer]) + ynt) * 0.5f * d[dn] * d[s];
}

// ---------------- W pack: MFMA B-fragment order ----------------

__global__ void wb_k(const float* __restrict__ w, unsigned short* __restrict__ wb) {
    int t = blockIdx.x * blockDim.x + threadIdx.x;   // 8192 threads
    if (t >= 8192) return;
    int lane = t & 63;
    int ct   = (t >> 6) & 7;
    int ks   = t >> 9;
    int row  = ct * 16 + (lane & 15);
    int kb   = ks * 32 + (lane >> 4) * 8;
    const float* p = &w[(size_t)row * IN_DIM + kb];
    float4 v0 = *(const float4*)p, v1 = *(const float4*)(p + 4);
    uint4 pk;
    pk.x = pk2(v0.x, v0.y);
    pk.y = pk2(v0.z, v0.w);
    pk.z = pk2(v1.x, v1.y);
    pk.w = pk2(v1.z, v1.w);
    *(uint4*)&wb[(size_t)t * 8] = pk;
}

// ---------------- t1 (global_load_lds staged bf16 MFMA) + fused L0 gate ------

__launch_bounds__(256)
__global__ void t1_k(const float* __restrict__ h, const unsigned short* __restrict__ wb,
                     const float* __restrict__ bias, const float* __restrict__ gw0,
                     unsigned short* __restrict__ xb0,
                     float* __restrict__ gd0, float* __restrict__ gs0) {
    __shared__ float At[16 * LDS_ROW];      // 33 KB staged fp32 tile
    __shared__ float red[4][4][4][2];       // gate partials [wave][quad][r][pd|ps]
    int tid  = threadIdx.x;
    int lane = tid & 63;
    int wv   = tid >> 6;
    int l15  = lane & 15;
    int quad = lane >> 4;
    int rowb = blockIdx.x * 16;             // 50000 = 3125*16, no tail

#pragma unroll
    for (int i = 0; i < 8; ++i) {
        int c    = wv * 8 + i;
        int row  = c >> 1, half = c & 1;
        const float* gsrc = &h[(size_t)(rowb + row) * IN_DIM + half * 256 + lane * 4];
        float* ldst = &At[row * LDS_ROW + half * 256];
        __builtin_amdgcn_global_load_lds(
            (const __attribute__((address_space(1))) unsigned int*)gsrc,
            (__attribute__((address_space(3))) unsigned int*)ldst, 16, 0, 0);
    }
    __syncthreads();

    int ct0 = wv * 2;
    const unsigned short* bp = &wb[(size_t)lane * 8];
    const float* arp = &At[l15 * LDS_ROW + quad * 8];
    f32x4 acc[2];
    acc[0] = (f32x4){0.f, 0.f, 0.f, 0.f};
    acc[1] = (f32x4){0.f, 0.f, 0.f, 0.f};
#pragma unroll 4
    for (int ks = 0; ks < 16; ++ks) {
        float4 a0 = *(const float4*)(arp + ks * 32);
        float4 a1 = *(const float4*)(arp + ks * 32 + 4);
        bf16v8 av;
        av[0] = (__bf16)a0.x; av[1] = (__bf16)a0.y;
        av[2] = (__bf16)a0.z; av[3] = (__bf16)a0.w;
        av[4] = (__bf16)a1.x; av[5] = (__bf16)a1.y;
        av[6] = (__bf16)a1.z; av[7] = (__bf16)a1.w;
        bf16x8 af = __builtin_bit_cast(bf16x8, av);
        bf16x8 b0 = *(const bf16x8*)(bp + (size_t)(ks * 8 + ct0) * 512);
        bf16x8 b1 = *(const bf16x8*)(bp + (size_t)(ks * 8 + ct0 + 1) * 512);
        acc[0] = __builtin_amdgcn_mfma_f32_16x16x32_bf16(af, b0, acc[0], 0, 0, 0);
        acc[1] = __builtin_amdgcn_mfma_f32_16x16x32_bf16(af, b1, acc[1], 0, 0, 0);
    }

    float pd[4] = {0.f, 0.f, 0.f, 0.f}, ps[4] = {0.f, 0.f, 0.f, 0.f};
#pragma unroll
    for (int ct = 0; ct < 2; ++ct) {
        int o = (ct0 + ct) * 16 + l15;
        float b = bias[o];
        float wd = gw0[o], wsv = gw0[128 + o];
#pragma unroll
        for (int r = 0; r < 4; ++r) {
            float v = acc[ct][r] + b;
            v = v > 0.f ? v : 0.f;
            int node = rowb + quad * 4 + r;
            xb0[(size_t)node * HID + o] = f2bfu(v);
            pd[r] += v * wd; ps[r] += v * wsv;
        }
    }
#pragma unroll
    for (int m = 1; m < 16; m <<= 1) {
#pragma unroll
        for (int r = 0; r < 4; ++r) {
            pd[r] += __shfl_xor(pd[r], m);
            ps[r] += __shfl_xor(ps[r], m);
        }
    }
    if (l15 == 0) {
#pragma unroll
        for (int r = 0; r < 4; ++r) {
            red[wv][quad][r][0] = pd[r];
            red[wv][quad][r][1] = ps[r];
        }
    }
    __syncthreads();
    if (wv == 0 && lane < 16) {
        int q = lane >> 2, r = lane & 3;
        float sd = red[0][q][r][0] + red[1][q][r][0] + red[2][q][r][0] + red[3][q][r][0];
        float ss = red[0][q][r][1] + red[1][q][r][1] + red[2][q][r][1] + red[3][q][r][1];
        gd0[rowb + lane] = sd;
        gs0[rowb + lane] = ss;
    }
}

// ---------------- aggregation v6 + optional fused next-layer gate -----
// One wave per dst node. Coefficients are PRECOMPUTED (coef_k) so the inner
// loop has no tanh, no gs/d gathers, and NO __shfl: each 16-lane group
// broadcast-loads csr2[e]/coef[e] (same address per group, merged request;
// addresses depend only on the trip index -> issuable arbitrarily early).
// Depth-3 rotating pipeline on the xb row gathers: 12 rows in flight/wave.
// Pad lanes/trips carry cf=0, s=0 -> harmless row-0 gather, contributes 0.

__global__ void agg_k(const unsigned short* __restrict__ xb,
                      const unsigned short* __restrict__ rb,
                      const int* __restrict__ rowptr, const int2* __restrict__ csr2,
                      const float* __restrict__ coef,
                      const float* __restrict__ gw_next,
                      float* __restrict__ gd_out, float* __restrict__ gs_out,
                      unsigned short* __restrict__ xb_out) {
    int t = blockIdx.x * blockDim.x + threadIdx.x;
    int nid = t >> 6, lane = t & 63;
    if (nid >= N_NODES) return;
    int l15 = lane & 15, eg = lane >> 4;
    float acc[8];
#pragma unroll
    for (int j = 0; j < 8; j++) acc[j] = 0.f;
    if (lane < 16) {
        uint4 rv = *(const uint4*)&rb[(size_t)nid * HID + l15 * 8];
        acc[0] = EPS * bf_lo(rv.x); acc[1] = EPS * bf_hi(rv.x);
        acc[2] = EPS * bf_lo(rv.y); acc[3] = EPS * bf_hi(rv.y);
        acc[4] = EPS * bf_lo(rv.z); acc[5] = EPS * bf_hi(rv.z);
        acc[6] = EPS * bf_lo(rv.w); acc[7] = EPS * bf_hi(rv.w);
    }
    int e0 = rowptr[nid], e1 = rowptr[nid + 1];
    int nt = (e1 - e0 + 3) >> 2;            // trips of 4 edges (16 lanes/edge)

    // edge-meta fetch for trip tt (group eg's edge): guard-free via e<e1
    auto fetch = [&](int tt, float& cf, int& s) {
        int e = e0 + tt * 4 + eg;
        cf = 0.f; s = 0;
        if (e < e1) { int2 pr = csr2[e]; cf = coef[e]; s = pr.x & 0xffff; }
    };
    auto ldx = [&](int s) {
        return *(const uint4*)&xb[(size_t)s * HID + l15 * 8];
    };

    float cf0, cf1, cf2; int s0, s1, s2;
    fetch(0, cf0, s0); fetch(1, cf1, s1); fetch(2, cf2, s2);
    uint4 v0 = ldx(s0), v1 = ldx(s1), v2 = ldx(s2);
    for (int tt = 0; tt < nt; tt++) {
        acc[0] += cf0 * bf_lo(v0.x); acc[1] += cf0 * bf_hi(v0.x);
        acc[2] += cf0 * bf_lo(v0.y); acc[3] += cf0 * bf_hi(v0.y);
        acc[4] += cf0 * bf_lo(v0.z); acc[5] += cf0 * bf_hi(v0.z);
        acc[6] += cf0 * bf_lo(v0.w); acc[7] += cf0 * bf_hi(v0.w);
        cf0 = cf1; v0 = v1; s0 = s1;
        cf1 = cf2; v1 = v2; s1 = s2;
        fetch(tt + 3, cf2, s2);
        v2 = ldx(s2);
    }
    // fold the 4 edge-groups: after this ALL lanes hold the full row chunk for l15
#pragma unroll
    for (int j = 0; j < 8; j++) acc[j] += __shfl_xor(acc[j], 32);
#pragma unroll
    for (int j = 0; j < 8; j++) acc[j] += __shfl_xor(acc[j], 16);
    if (lane < 16) {
        uint4 pk;
        pk.x = pk2(acc[0], acc[1]);
        pk.y = pk2(acc[2], acc[3]);
        pk.z = pk2(acc[4], acc[5]);
        pk.w = pk2(acc[6], acc[7]);
        *(uint4*)&xb_out[(size_t)nid * HID + l15 * 8] = pk;
    }
    // fused next-layer gate dots (layer 0 only)
    if (gw_next) {
        float pd = 0.f, psv = 0.f;
#pragma unroll
        for (int j = 0; j < 8; j++) {
            int o = l15 * 8 + j;
            pd  += acc[j] * gw_next[o];
            psv += acc[j] * gw_next[128 + o];
        }
#pragma unroll
        for (int m = 1; m < 16; m <<= 1) {
            pd  += __shfl_xor(pd, m);
            psv += __shfl_xor(psv, m);
        }
        if (lane == 0) { gd_out[nid] = pd; gs_out[nid] = psv; }
    }
}

// ---------------- t2 + log_softmax: 64-node tile per block (bf16 x) ----------------

__launch_bounds__(256)
__global__ void out_k(const unsigned short* __restrict__ xb, const float* __restrict__ w,
                      const float* __restrict__ bias, float* __restrict__ out) {
    __shared__ float As[64][132];   // 64 nodes x 128 k
    __shared__ float Bs[64][132];   // 64 outs  x 128 k
    int tid = threadIdx.x;
    int n0  = blockIdx.x * 64;
#pragma unroll
    for (int j = 0; j < 4; j++) {
        int c8 = tid + j * 256;          // 1024 chunks of 8 bf16
        int r = c8 >> 4, c = (c8 & 15) * 8;
        int gr = n0 + r;
        uint4 v = make_uint4(0, 0, 0, 0);
        if (gr < N_NODES) v = *(const uint4*)&xb[(size_t)gr * HID + c];
        *(float4*)&As[r][c]     = make_float4(bf_lo(v.x), bf_hi(v.x), bf_lo(v.y), bf_hi(v.y));
        *(float4*)&As[r][c + 4] = make_float4(bf_lo(v.z), bf_hi(v.z), bf_lo(v.w), bf_hi(v.w));
    }
#pragma unroll
    for (int j = 0; j < 8; j++) {
        int f4 = tid + j * 256;
        int r = f4 >> 5, c = (f4 & 31) * 4;
        *(float4*)&Bs[r][c] = *(const float4*)&w[r * HID + c];
    }
    __syncthreads();
    int tn = tid >> 4, to = tid & 15;
    float acc[4][4];
#pragma unroll
    for (int i = 0; i < 4; i++)
#pragma unroll
        for (int j = 0; j < 4; j++) acc[i][j] = 0.0f;
    // unroll capped at 2: full unroll was the VGPR=256 spill (R1)
#pragma unroll 2
    for (int k = 0; k < HID; k += 4) {
        float4 av[4], bv[4];
#pragma unroll
        for (int i = 0; i < 4; i++) av[i] = *(const float4*)&As[tn + 16 * i][k];
#pragma unroll
        for (int j = 0; j < 4; j++) bv[j] = *(const float4*)&Bs[to + 16 * j][k];
#pragma unroll
        for (int i = 0; i < 4; i++)
#pragma unroll
            for (int j = 0; j < 4; j++) {
                acc[i][j] += av[i].x * bv[j].x;
                acc[i][j] += av[i].y * bv[j].y;
                acc[i][j] += av[i].z * bv[j].z;
                acc[i][j] += av[i].w * bv[j].w;
            }
    }
    float bj[4];
#pragma unroll
    for (int j = 0; j < 4; j++) bj[j] = bias[to + 16 * j];
#pragma unroll
    for (int i = 0; i < 4; i++) {
        float v[4];
        float m = -1e30f;
#pragma unroll
        for (int j = 0; j < 4; j++) { v[j] = acc[i][j] + bj[j]; m = fmaxf(m, v[j]); }
#pragma unroll
        for (int s = 1; s < 16; s <<= 1) m = fmaxf(m, __shfl_xor(m, s));
        float sum = 0.f;
#pragma unroll
        for (int j = 0; j < 4; j++) sum += __expf(v[j] - m);
#pragma unroll
        for (int s = 1; s < 16; s <<= 1) sum += __shfl_xor(sum, s);
        float lse = m + __logf(sum);
        int r = n0 + tn + 16 * i;
        if (r < N_NODES) {
#pragma unroll
            for (int j = 0; j < 4; j++) out[r * OUT_DIM + to + 16 * j] = v[j] - lse;
        }
    }
}

// ---------------- launcher ----------------

extern "C" void kernel_launch(void* const* d_in, const int* in_sizes, int n_in,
                              void* d_out, int out_size, void* d_ws, size_t ws_size,
                              hipStream_t stream) {
    const float* h    = (const float*)d_in[0];
    const float* d    = (const float*)d_in[1];
    const float* t1_w = (const float*)d_in[2];
    const float* t1_b = (const float*)d_in[3];
    const float* gw   = (const float*)d_in[4];   // [2][256]
    const float* gb   = (const float*)d_in[5];   // [2]
    const float* t2_w = (const float*)d_in[6];   // [64][128]
    const float* t2_b = (const float*)d_in[7];
    const float* yw   = (const float*)d_in[8];
    const float* nw   = (const float*)d_in[9];
    const int* src    = (const int*)d_in[10];
    const int* dst    = (const int*)d_in[11];
    const int* yn     = (const int*)d_in[12];
    float* outp = (float*)d_out;

    char* ws = (char*)d_ws;
    size_t off = 0;
    auto alloc = [&](size_t bytes) {
        void* p = ws + off;
        off = (off + bytes + 255) & ~(size_t)255;
        return p;
    };
    unsigned short* xb0 = (unsigned short*)alloc((size_t)N_NODES * HID * 2);
    unsigned short* xb1 = (unsigned short*)alloc((size_t)N_NODES * HID * 2);
    unsigned short* xb2 = (unsigned short*)alloc((size_t)N_NODES * HID * 2);
    unsigned short* wb  = (unsigned short*)alloc((size_t)8192 * 8 * 2);
    float* gd0    = (float*)alloc((size_t)N_NODES * 4);
    float* gs0    = (float*)alloc((size_t)N_NODES * 4);
    float* gd1    = (float*)alloc((size_t)N_NODES * 4);
    float* gs1    = (float*)alloc((size_t)N_NODES * 4);
    int*   rowptr = (int*)alloc((size_t)(N_NODES + 1) * 4);
    int*   cursor = (int*)alloc((size_t)N_NODES * 4);
    int2*  csr2   = (int2*)alloc((size_t)N_EDGES * 8);
    float* coef   = (float*)alloc((size_t)N_EDGES * 4);
    int*   partials = (int*)alloc(64 * 4);
    int*   bofs     = (int*)alloc(64 * 4);
    (void)ws_size; (void)n_in; (void)in_sizes; (void)out_size;

    // CSR build: deg derived from d (no histogram, no memset)
    partial_k<<<SCAN_BLOCKS, 256, 0, stream>>>(d, partials);
    scanp_k<<<1, 64, 0, stream>>>(partials, bofs, rowptr);
    scanw_k<<<SCAN_BLOCKS, 256, 0, stream>>>(d, bofs, rowptr, cursor);
    fill_k<<<(N_EDGES + 255) / 256, 256, 0, stream>>>(src, dst, yn, cursor, csr2);

    // W pack (tiny) + t1 with fused layer-0 gate (global_load_lds staged)
    wb_k<<<32, 256, 0, stream>>>(t1_w, wb);
    t1_k<<<N_NODES / 16, 256, 0, stream>>>(h, wb, t1_b, gw, xb0, gd0, gs0);

    int wave_blocks = (N_NODES * 64 + 255) / 256;   // one wave per node
    int edge_blocks = (N_EDGES + 255) / 256;

    // layer 0: coef from (gd0,gs0); gather xb0, residual xb0 -> xb1, fused L1 gate
    coef_k<<<edge_blocks, 256, 0, stream>>>(csr2, d, gd0, gs0, gb, 0, yw, nw, coef);
    agg_k<<<wave_blocks, 256, 0, stream>>>(xb0, xb0, rowptr, csr2, coef,
                                           gw + 256, gd1, gs1, xb1);
    // layer 1: coef from (gd1,gs1); gather xb1, residual xb0 -> xb2
    coef_k<<<edge_blocks, 256, 0, stream>>>(csr2, d, gd1, gs1, gb, 1, yw, nw, coef);
    agg_k<<<wave_blocks, 256, 0, stream>>>(xb1, xb0, rowptr, csr2, coef,
                                           (const float*)nullptr,
                                           (float*)nullptr, (float*)nullptr, xb2);

    // t2 + log_softmax (bf16 x)
    out_k<<<(N_NODES + 63) / 64, 256, 0, stream>>>(xb2, t2_w, t2_b, outp);
}

// Round 4
// 336.485 us; speedup vs baseline: 1.1113x; 1.1113x over previous
//
#include <hip/hip_runtime.h>
#include <math.h>

#define N_NODES 50000
#define N_EDGES 800000
#define IN_DIM  512
#define HID     128
#define OUT_DIM 64
#define EPS     0.3f

#define SCAN_BLOCKS 49   // ceil(50000 / 1024)
#define LDS_ROW 516      // 512 + 4 dword pad -> 2-way bank aliasing (free, m136)

typedef __attribute__((ext_vector_type(8))) short bf16x8;
typedef __attribute__((ext_vector_type(8))) __bf16 bf16v8;
typedef __attribute__((ext_vector_type(4))) float f32x4;

__device__ __forceinline__ float fast_tanh(float x) {
    // tanh(x) = 1 - 2/(exp(2x)+1); saturates correctly at +/-inf
    return 1.0f - 2.0f / (__expf(2.0f * x) + 1.0f);
}

// f32 -> bf16 via native cast: compiler emits v_cvt_pk_bf16_f32 (RNE).
__device__ __forceinline__ unsigned short f2bfu(float f) {
    return __builtin_bit_cast(unsigned short, (__bf16)f);
}
__device__ __forceinline__ unsigned pk2(float lo, float hi) {
    return (unsigned)f2bfu(lo) | ((unsigned)f2bfu(hi) << 16);
}
__device__ __forceinline__ float bf_lo(unsigned u) { return __uint_as_float(u << 16); }
__device__ __forceinline__ float bf_hi(unsigned u) { return __uint_as_float(u & 0xffff0000u); }

// degree recovered from input d = rsqrt(deg+1): deg = round(1/d^2) - 1.
__device__ __forceinline__ int deg_of(float dv) {
    return (int)(1.0f / (dv * dv) + 0.5f) - 1;
}

// ---------------- CSR build (no histogram: deg derived from d) ----------------

__global__ void partial_k(const float* __restrict__ d, int* __restrict__ partials) {
    int base = blockIdx.x * 1024 + threadIdx.x * 4;
    int s = 0;
#pragma unroll
    for (int j = 0; j < 4; j++) if (base + j < N_NODES) s += deg_of(d[base + j]);
#pragma unroll
    for (int off = 32; off; off >>= 1) s += __shfl_down(s, off);
    __shared__ int ws[4];
    int lane = threadIdx.x & 63, wv = threadIdx.x >> 6;
    if (lane == 0) ws[wv] = s;
    __syncthreads();
    if (threadIdx.x == 0) partials[blockIdx.x] = ws[0] + ws[1] + ws[2] + ws[3];
}

__global__ void scanp_k(const int* __restrict__ partials, int* __restrict__ bofs,
                        int* __restrict__ rowptr) {
    if (threadIdx.x == 0) {
        int a = 0;
        for (int i = 0; i < SCAN_BLOCKS; i++) { bofs[i] = a; a += partials[i]; }
        rowptr[N_NODES] = a;
    }
}

__global__ void scanw_k(const float* __restrict__ d, const int* __restrict__ bofs,
                        int* __restrict__ rowptr, int* __restrict__ cursor) {
    int base = blockIdx.x * 1024 + threadIdx.x * 4;
    int v[4]; int s = 0;
#pragma unroll
    for (int j = 0; j < 4; j++) {
        v[j] = (base + j < N_NODES) ? deg_of(d[base + j]) : 0;
        s += v[j];
    }
    int lane = threadIdx.x & 63, wv = threadIdx.x >> 6;
    int sc = s;
#pragma unroll
    for (int off = 1; off < 64; off <<= 1) {
        int t = __shfl_up(sc, off);
        if (lane >= off) sc += t;
    }
    __shared__ int wtot[4];
    if (lane == 63) wtot[wv] = sc;
    __syncthreads();
    int wof = 0;
    for (int w = 0; w < wv; w++) wof += wtot[w];
    int excl = bofs[blockIdx.x] + wof + (sc - s);
#pragma unroll
    for (int j = 0; j < 4; j++) {
        if (base + j < N_NODES) { rowptr[base + j] = excl; cursor[base + j] = excl; }
        excl += v[j];
    }
}

// ---------------- W pack: MFMA B-fragment order ----------------

__global__ void wb_k(const float* __restrict__ w, unsigned short* __restrict__ wb) {
    int t = blockIdx.x * blockDim.x + threadIdx.x;   // 8192 threads
    if (t >= 8192) return;
    int lane = t & 63;
    int ct   = (t >> 6) & 7;
    int ks   = t >> 9;
    int row  = ct * 16 + (lane & 15);
    int kb   = ks * 32 + (lane >> 4) * 8;
    const float* p = &w[(size_t)row * IN_DIM + kb];
    float4 v0 = *(const float4*)p, v1 = *(const float4*)(p + 4);
    uint4 pk;
    pk.x = pk2(v0.x, v0.y);
    pk.y = pk2(v0.z, v0.w);
    pk.z = pk2(v1.x, v1.y);
    pk.w = pk2(v1.z, v1.w);
    *(uint4*)&wb[(size_t)t * 8] = pk;
}

// ---------------- fused t1 (MFMA tile) | fill (CSR scatter) ----------------
// R3 post-mortem: fill_k is transaction-latency-bound (HBM 11%, VALU 0.4%,
// occupancy 56%) -> every pipe idle. t1 is MFMA/LDS-bound with the VMEM queue
// idle. They are independent; co-scheduling them (m114: waves on different
// pipes overlap at ~max, not sum) hides ~all of fill under t1's compute.
// Interleaved block types keep both resident on every CU through the dispatch.
// fill half: 800000 = 3125 * 256 exactly -> guard-free.

__launch_bounds__(256)
__global__ void t1fill_k(const float* __restrict__ h, const unsigned short* __restrict__ wb,
                         const float* __restrict__ bias, const float* __restrict__ gw0,
                         unsigned short* __restrict__ xb0,
                         float* __restrict__ gd0, float* __restrict__ gs0,
                         const int* __restrict__ src, const int* __restrict__ dst,
                         const int* __restrict__ yn, int* __restrict__ cursor,
                         int* __restrict__ csr) {
    __shared__ float At[16 * LDS_ROW];      // 33 KB staged fp32 tile (t1 blocks)
    __shared__ float red[4][4][4][2];       // gate partials [wave][quad][r][pd|ps]

    if (blockIdx.x & 1) {
        // ---- fill half: block (blockIdx>>1), one edge per thread ----
        int e = (blockIdx.x >> 1) * 256 + threadIdx.x;   // < 800000 exactly
        int dv = dst[e];
        int pos = atomicAdd(&cursor[dv], 1);
        csr[pos] = src[e] | (yn[e] << 31);   // src < 2^17, yn packed in sign bit
        return;
    }

    // ---- t1 half ----
    int tid  = threadIdx.x;
    int lane = tid & 63;
    int wv   = tid >> 6;
    int l15  = lane & 15;
    int quad = lane >> 4;
    int rowb = (blockIdx.x >> 1) * 16;      // 50000 = 3125*16, no tail

    // stage: 32 chunks of 1KB (chunk c: row c>>1, half c&1), 8 per wave.
    // lds dest is wave-uniform base + lane*16 (HW) -> chunk stays inside one
    // padded row, so the pad never lands mid-chunk (m104/m108 caveat).
#pragma unroll
    for (int i = 0; i < 8; ++i) {
        int c    = wv * 8 + i;
        int row  = c >> 1, half = c & 1;
        const float* gsrc = &h[(size_t)(rowb + row) * IN_DIM + half * 256 + lane * 4];
        float* ldst = &At[row * LDS_ROW + half * 256];
        __builtin_amdgcn_global_load_lds(
            (const __attribute__((address_space(1))) unsigned int*)gsrc,
            (__attribute__((address_space(3))) unsigned int*)ldst, 16, 0, 0);
    }
    __syncthreads();

    // compute: wave wv covers output cols [wv*32, wv*32+32) = ct0, ct0+1
    int ct0 = wv * 2;
    const unsigned short* bp = &wb[(size_t)lane * 8];
    const float* arp = &At[l15 * LDS_ROW + quad * 8];
    f32x4 acc[2];
    acc[0] = (f32x4){0.f, 0.f, 0.f, 0.f};
    acc[1] = (f32x4){0.f, 0.f, 0.f, 0.f};
#pragma unroll 4
    for (int ks = 0; ks < 16; ++ks) {
        float4 a0 = *(const float4*)(arp + ks * 32);
        float4 a1 = *(const float4*)(arp + ks * 32 + 4);
        bf16v8 av;
        av[0] = (__bf16)a0.x; av[1] = (__bf16)a0.y;
        av[2] = (__bf16)a0.z; av[3] = (__bf16)a0.w;
        av[4] = (__bf16)a1.x; av[5] = (__bf16)a1.y;
        av[6] = (__bf16)a1.z; av[7] = (__bf16)a1.w;
        bf16x8 af = __builtin_bit_cast(bf16x8, av);
        bf16x8 b0 = *(const bf16x8*)(bp + (size_t)(ks * 8 + ct0) * 512);
        bf16x8 b1 = *(const bf16x8*)(bp + (size_t)(ks * 8 + ct0 + 1) * 512);
        acc[0] = __builtin_amdgcn_mfma_f32_16x16x32_bf16(af, b0, acc[0], 0, 0, 0);
        acc[1] = __builtin_amdgcn_mfma_f32_16x16x32_bf16(af, b1, acc[1], 0, 0, 0);
    }

    // epilogue: bias+relu, store bf16, gate partials for this wave's 32 cols
    float pd[4] = {0.f, 0.f, 0.f, 0.f}, ps[4] = {0.f, 0.f, 0.f, 0.f};
#pragma unroll
    for (int ct = 0; ct < 2; ++ct) {
        int o = (ct0 + ct) * 16 + l15;
        float b = bias[o];
        float wd = gw0[o], wsv = gw0[128 + o];
#pragma unroll
        for (int r = 0; r < 4; ++r) {
            float v = acc[ct][r] + b;
            v = v > 0.f ? v : 0.f;
            int node = rowb + quad * 4 + r;
            xb0[(size_t)node * HID + o] = f2bfu(v);
            pd[r] += v * wd; ps[r] += v * wsv;
        }
    }
    // reduce over the 16 lanes of l15
#pragma unroll
    for (int m = 1; m < 16; m <<= 1) {
#pragma unroll
        for (int r = 0; r < 4; ++r) {
            pd[r] += __shfl_xor(pd[r], m);
            ps[r] += __shfl_xor(ps[r], m);
        }
    }
    if (l15 == 0) {
#pragma unroll
        for (int r = 0; r < 4; ++r) {
            red[wv][quad][r][0] = pd[r];
            red[wv][quad][r][1] = ps[r];
        }
    }
    __syncthreads();
    // cross-wave sum: 16 rows handled by lanes 0..15 of wave 0
    if (wv == 0 && lane < 16) {
        int q = lane >> 2, r = lane & 3;
        float sd = red[0][q][r][0] + red[1][q][r][0] + red[2][q][r][0] + red[3][q][r][0];
        float ss = red[0][q][r][1] + red[1][q][r][1] + red[2][q][r][1] + red[3][q][r][1];
        gd0[rowb + lane] = sd;
        gs0[rowb + lane] = ss;
    }
}

// ---------------- aggregation (coef inline, R1-proven v5) + fused next gate -----
// One wave per dst node. Batch phase: lane e computes coef for edge e0+lane.
// Gather phase: 4 edges/trip, 16 lanes/edge, coef/src broadcast via __shfl.
// Software-pipelined (prefetch trip t+1's shfl+gather while FMA'ing trip t).
// R2/R3 lesson: do NOT hoist coef to a separate edge-parallel kernel and do NOT
// broadcast-load per-trip edge meta from memory -- that traded cheap shfls for
// extra VMEM issues and regressed ~30us. This v5 form measured 340.5us total.
// rb (residual = original t1 output x0) is SEPARATE from xb (gather source).

__global__ void agg_k(const unsigned short* __restrict__ xb,
                      const unsigned short* __restrict__ rb,
                      const int* __restrict__ rowptr, const int* __restrict__ csr,
                      const float* __restrict__ d,
                      const float* __restrict__ gd, const float* __restrict__ gs,
                      const float* __restrict__ gb, int layer,
                      const float* __restrict__ yw, const float* __restrict__ nw,
                      const float* __restrict__ gw_next,
                      float* __restrict__ gd_out, float* __restrict__ gs_out,
                      unsigned short* __restrict__ xb_out) {
    int t = blockIdx.x * blockDim.x + threadIdx.x;
    int nid = t >> 6, lane = t & 63;
    if (nid >= N_NODES) return;
    int l15 = lane & 15, eg = lane >> 4;
    float acc[8];
#pragma unroll
    for (int j = 0; j < 8; j++) acc[j] = 0.f;
    if (lane < 16) {
        uint4 rv = *(const uint4*)&rb[(size_t)nid * HID + l15 * 8];
        acc[0] = EPS * bf_lo(rv.x); acc[1] = EPS * bf_hi(rv.x);
        acc[2] = EPS * bf_lo(rv.y); acc[3] = EPS * bf_hi(rv.y);
        acc[4] = EPS * bf_lo(rv.z); acc[5] = EPS * bf_hi(rv.z);
        acc[6] = EPS * bf_lo(rv.w); acc[7] = EPS * bf_hi(rv.w);
    }
    float gdn = gd[nid] + gb[layer];
    float dn  = d[nid];
    float ty  = fast_tanh(yw[0]);
    float tno = fast_tanh(nw[0]);
    int e0 = rowptr[nid], e1 = rowptr[nid + 1];
    for (int b0 = e0; b0 < e1; b0 += 64) {
        int e = b0 + lane;
        float cf = 0.f; int sidx = 0;
        if (e < e1) {
            int p = csr[e];
            int s = p & 0x7fffffff;
            float ynt = (p < 0) ? ty : tno;
            cf = (fast_tanh(gdn + gs[s]) + ynt) * 0.5f * dn * d[s];
            sidx = s;
        }
        int trips = e1 - b0; if (trips > 64) trips = 64;
        // prime trip 0
        float cfA = __shfl(cf, eg);
        int   sA  = __shfl(sidx, eg);
        uint4 vA  = *(const uint4*)&xb[(size_t)sA * HID + l15 * 8];
        for (int t4 = 0; t4 < trips; t4 += 4) {
            // prefetch trip t4+4 (wave-uniform branch; nx <= 63 always since
            // t4 <= 56 whenever the guard passes, so no shfl wrap)
            float cfB = 0.f; uint4 vB = make_uint4(0, 0, 0, 0);
            if (t4 + 4 < trips) {
                int nx = t4 + 4 + eg;
                cfB = __shfl(cf, nx);
                int sB = __shfl(sidx, nx);
                vB = *(const uint4*)&xb[(size_t)sB * HID + l15 * 8];
            }
            acc[0] += cfA * bf_lo(vA.x); acc[1] += cfA * bf_hi(vA.x);
            acc[2] += cfA * bf_lo(vA.y); acc[3] += cfA * bf_hi(vA.y);
            acc[4] += cfA * bf_lo(vA.z); acc[5] += cfA * bf_hi(vA.z);
            acc[6] += cfA * bf_lo(vA.w); acc[7] += cfA * bf_hi(vA.w);
            cfA = cfB; vA = vB;
        }
    }
    // fold the 4 edge-groups: after this ALL lanes hold the full row chunk for l15
#pragma unroll
    for (int j = 0; j < 8; j++) acc[j] += __shfl_xor(acc[j], 32);
#pragma unroll
    for (int j = 0; j < 8; j++) acc[j] += __shfl_xor(acc[j], 16);
    if (lane < 16) {
        uint4 pk;
        pk.x = pk2(acc[0], acc[1]);
        pk.y = pk2(acc[2], acc[3]);
        pk.z = pk2(acc[4], acc[5]);
        pk.w = pk2(acc[6], acc[7]);
        *(uint4*)&xb_out[(size_t)nid * HID + l15 * 8] = pk;
    }
    // fused next-layer gate dots (layer 0 only)
    if (gw_next) {
        float pd = 0.f, psv = 0.f;
#pragma unroll
        for (int j = 0; j < 8; j++) {
            int o = l15 * 8 + j;
            pd  += acc[j] * gw_next[o];
            psv += acc[j] * gw_next[128 + o];
        }
#pragma unroll
        for (int m = 1; m < 16; m <<= 1) {
            pd  += __shfl_xor(pd, m);
            psv += __shfl_xor(psv, m);
        }
        if (lane == 0) { gd_out[nid] = pd; gs_out[nid] = psv; }
    }
}

// ---------------- t2 + log_softmax: 64-node tile per block (bf16 x) ----------------

__launch_bounds__(256)
__global__ void out_k(const unsigned short* __restrict__ xb, const float* __restrict__ w,
                      const float* __restrict__ bias, float* __restrict__ out) {
    __shared__ float As[64][132];   // 64 nodes x 128 k
    __shared__ float Bs[64][132];   // 64 outs  x 128 k
    int tid = threadIdx.x;
    int n0  = blockIdx.x * 64;
#pragma unroll
    for (int j = 0; j < 4; j++) {
        int c8 = tid + j * 256;          // 1024 chunks of 8 bf16
        int r = c8 >> 4, c = (c8 & 15) * 8;
        int gr = n0 + r;
        uint4 v = make_uint4(0, 0, 0, 0);
        if (gr < N_NODES) v = *(const uint4*)&xb[(size_t)gr * HID + c];
        *(float4*)&As[r][c]     = make_float4(bf_lo(v.x), bf_hi(v.x), bf_lo(v.y), bf_hi(v.y));
        *(float4*)&As[r][c + 4] = make_float4(bf_lo(v.z), bf_hi(v.z), bf_lo(v.w), bf_hi(v.w));
    }
#pragma unroll
    for (int j = 0; j < 8; j++) {
        int f4 = tid + j * 256;
        int r = f4 >> 5, c = (f4 & 31) * 4;
        *(float4*)&Bs[r][c] = *(const float4*)&w[r * HID + c];
    }
    __syncthreads();
    int tn = tid >> 4, to = tid & 15;
    float acc[4][4];
#pragma unroll
    for (int i = 0; i < 4; i++)
#pragma unroll
        for (int j = 0; j < 4; j++) acc[i][j] = 0.0f;
    // unroll capped at 2: full unroll was the VGPR=256 spill (R1)
#pragma unroll 2
    for (int k = 0; k < HID; k += 4) {
        float4 av[4], bv[4];
#pragma unroll
        for (int i = 0; i < 4; i++) av[i] = *(const float4*)&As[tn + 16 * i][k];
#pragma unroll
        for (int j = 0; j < 4; j++) bv[j] = *(const float4*)&Bs[to + 16 * j][k];
#pragma unroll
        for (int i = 0; i < 4; i++)
#pragma unroll
            for (int j = 0; j < 4; j++) {
                acc[i][j] += av[i].x * bv[j].x;
                acc[i][j] += av[i].y * bv[j].y;
                acc[i][j] += av[i].z * bv[j].z;
                acc[i][j] += av[i].w * bv[j].w;
            }
    }
    float bj[4];
#pragma unroll
    for (int j = 0; j < 4; j++) bj[j] = bias[to + 16 * j];
#pragma unroll
    for (int i = 0; i < 4; i++) {
        float v[4];
        float m = -1e30f;
#pragma unroll
        for (int j = 0; j < 4; j++) { v[j] = acc[i][j] + bj[j]; m = fmaxf(m, v[j]); }
#pragma unroll
        for (int s = 1; s < 16; s <<= 1) m = fmaxf(m, __shfl_xor(m, s));
        float sum = 0.f;
#pragma unroll
        for (int j = 0; j < 4; j++) sum += __expf(v[j] - m);
#pragma unroll
        for (int s = 1; s < 16; s <<= 1) sum += __shfl_xor(sum, s);
        float lse = m + __logf(sum);
        int r = n0 + tn + 16 * i;
        if (r < N_NODES) {
#pragma unroll
            for (int j = 0; j < 4; j++) out[r * OUT_DIM + to + 16 * j] = v[j] - lse;
        }
    }
}

// ---------------- launcher ----------------

extern "C" void kernel_launch(void* const* d_in, const int* in_sizes, int n_in,
                              void* d_out, int out_size, void* d_ws, size_t ws_size,
                              hipStream_t stream) {
    const float* h    = (const float*)d_in[0];
    const float* d    = (const float*)d_in[1];
    const float* t1_w = (const float*)d_in[2];
    const float* t1_b = (const float*)d_in[3];
    const float* gw   = (const float*)d_in[4];   // [2][256]
    const float* gb   = (const float*)d_in[5];   // [2]
    const float* t2_w = (const float*)d_in[6];   // [64][128]
    const float* t2_b = (const float*)d_in[7];
    const float* yw   = (const float*)d_in[8];
    const float* nw   = (const float*)d_in[9];
    const int* src    = (const int*)d_in[10];
    const int* dst    = (const int*)d_in[11];
    const int* yn     = (const int*)d_in[12];
    float* outp = (float*)d_out;

    char* ws = (char*)d_ws;
    size_t off = 0;
    auto alloc = [&](size_t bytes) {
        void* p = ws + off;
        off = (off + bytes + 255) & ~(size_t)255;
        return p;
    };
    unsigned short* xb0 = (unsigned short*)alloc((size_t)N_NODES * HID * 2);
    unsigned short* xb1 = (unsigned short*)alloc((size_t)N_NODES * HID * 2);
    unsigned short* xb2 = (unsigned short*)alloc((size_t)N_NODES * HID * 2);
    unsigned short* wb  = (unsigned short*)alloc((size_t)8192 * 8 * 2);
    float* gd0    = (float*)alloc((size_t)N_NODES * 4);
    float* gs0    = (float*)alloc((size_t)N_NODES * 4);
    float* gd1    = (float*)alloc((size_t)N_NODES * 4);
    float* gs1    = (float*)alloc((size_t)N_NODES * 4);
    int*   rowptr = (int*)alloc((size_t)(N_NODES + 1) * 4);
    int*   cursor = (int*)alloc((size_t)N_NODES * 4);
    int*   csr    = (int*)alloc((size_t)N_EDGES * 4);
    int*   partials = (int*)alloc(64 * 4);
    int*   bofs     = (int*)alloc(64 * 4);
    (void)ws_size; (void)n_in; (void)in_sizes; (void)out_size;

    // CSR rowptr/cursor build: deg derived from d (no histogram, no memset)
    partial_k<<<SCAN_BLOCKS, 256, 0, stream>>>(d, partials);
    scanp_k<<<1, 64, 0, stream>>>(partials, bofs, rowptr);
    scanw_k<<<SCAN_BLOCKS, 256, 0, stream>>>(d, bofs, rowptr, cursor);

    // W pack (tiny), then fused t1|fill mega-kernel (interleaved block types)
    wb_k<<<32, 256, 0, stream>>>(t1_w, wb);
    t1fill_k<<<2 * (N_NODES / 16), 256, 0, stream>>>(h, wb, t1_b, gw, xb0, gd0, gs0,
                                                     src, dst, yn, cursor, csr);

    int wave_blocks = (N_NODES * 64 + 255) / 256;   // one wave per node

    // layer 0: gather xb0, residual xb0 -> xb1, fused layer-1 gate dots
    agg_k<<<wave_blocks, 256, 0, stream>>>(xb0, xb0, rowptr, csr, d, gd0, gs0, gb, 0,
                                           yw, nw, gw + 256, gd1, gs1, xb1);
    // layer 1: gather xb1, residual xb0 (raw is FIXED across layers) -> xb2
    agg_k<<<wave_blocks, 256, 0, stream>>>(xb1, xb0, rowptr, csr, d, gd1, gs1, gb, 1,
                                           yw, nw, (const float*)nullptr,
                                           (float*)nullptr, (float*)nullptr, xb2);

    // t2 + log_softmax (bf16 x)
    out_k<<<(N_NODES + 63) / 64, 256, 0, stream>>>(xb2, t2_w, t2_b, outp);
}